// Round 7
// baseline (403.401 us; speedup 1.0000x reference)
//
#include <hip/hip_runtime.h>
#include <cstdint>

// GCN forward on MI355X (gfx950). f32 in/out; bf16 MFMA with fp32 accum;
// bf16 intermediates; 4-byte packed CSR entries (src:u16 | weight:bf16).
// Chain (6): memset deg -> prep(transposes+count+rank) -> scan
//   -> [gemm1(128x256 tile) || scatter] -> mid(spmm1+bias+relu+gemm2, H in LDS)
//   -> spmm2+bias+log_softmax.

typedef unsigned short u16;
typedef unsigned int u32;
typedef __attribute__((ext_vector_type(8))) short bf16x8;
typedef __attribute__((ext_vector_type(4))) float f32x4;

#define N_NODES 50000
#define N_EDGES 800000
#define NFEAT 512
#define NHID 256
#define NCLASS 64
#define DEG_PAD 65536     // scan reads unguarded int4; zero-padded

#define GB1 391           // gemm1 blocks: ceil(50000/128)
#define SB  391           // scatter blocks: ceil(800000/2048)

__device__ __forceinline__ float bf2f(u16 h) {
    union { u32 u; float f; } c; c.u = ((u32)h) << 16; return c.f;
}
__device__ __forceinline__ u16 f2bf(float f) {
    union { float f; u32 u; } c; c.f = f;
    u32 u = c.u;
    return (u16)((u + 0x7fffu + ((u >> 16) & 1u)) >> 16);   // RNE
}
__device__ __forceinline__ u32 pk2(float a, float b) {
    return (u32)f2bf(a) | ((u32)f2bf(b) << 16);
}

// async global->LDS, 16B per lane; LDS dest = wave-uniform base + lane*16.
__device__ __forceinline__ void async16(const void* g, void* l) {
    __builtin_amdgcn_global_load_lds(
        (const __attribute__((address_space(1))) void*)(uintptr_t)g,
        (__attribute__((address_space(3))) void*)(uintptr_t)l, 16, 0, 0);
}

// ---------------- prep: W1/W2 transpose+cvt + degree count + rank ----------------
// blocks [0,512): W1T, [512,576): W2T, [576,967): count 8 edges/thread (int4 loads)

__global__ __launch_bounds__(256) void prep_kernel(
    const float* __restrict__ W1, u16* __restrict__ W1T,
    const float* __restrict__ W2, u16* __restrict__ W2T,
    const int* __restrict__ edst, int* __restrict__ deg, int* __restrict__ rank) {
    int b = blockIdx.x;
    if (b < 512) {
        int idx = b * 256 + threadIdx.x;           // W1T[256][512]
        int n = idx >> 9, k = idx & 511;
        W1T[idx] = f2bf(W1[(size_t)k * NHID + n]);
    } else if (b < 576) {
        int idx = (b - 512) * 256 + threadIdx.x;   // W2T[64][256]
        int n = idx >> 8, k = idx & 255;
        W2T[idx] = f2bf(W2[(size_t)k * NCLASS + n]);
    } else {
        int e0 = ((b - 576) * 256 + threadIdx.x) * 8;
        if (e0 < N_EDGES) {                        // 800000 % 8 == 0: full chunk
            int4 d0 = *(const int4*)(edst + e0);
            int4 d1 = *(const int4*)(edst + e0 + 4);
            int d[8] = {d0.x, d0.y, d0.z, d0.w, d1.x, d1.y, d1.z, d1.w};
            int r[8];
            #pragma unroll
            for (int i = 0; i < 8; ++i) r[i] = atomicAdd(&deg[d[i]], 1);
            *(int4*)(rank + e0)     = make_int4(r[0], r[1], r[2], r[3]);
            *(int4*)(rank + e0 + 4) = make_int4(r[4], r[5], r[6], r[7]);
        }
    }
}

// ---------------- scan: deg[0..n) -> rowstart[0..n] ----------------

__global__ __launch_bounds__(1024) void scan_kernel(const int* __restrict__ deg,
                                                    int* __restrict__ rowstart, int n) {
    __shared__ int wsum[16];
    __shared__ int s_carry;
    const int tid = threadIdx.x;
    const int lane = tid & 63, wid = tid >> 6;
    if (tid == 0) s_carry = 0;
    __syncthreads();
    const int CH = 16;
    for (int base = 0; base < DEG_PAD; base += 1024 * CH) {   // 4 iterations
        int i0 = base + tid * CH;
        int v[CH];
        #pragma unroll
        for (int q = 0; q < 4; ++q)
            *(int4*)&v[q * 4] = *(const int4*)(deg + i0 + q * 4);
        int s = 0;
        #pragma unroll
        for (int j = 0; j < CH; ++j) s += v[j];
        int incl = s;
        #pragma unroll
        for (int off = 1; off < 64; off <<= 1) {
            int t = __shfl_up(incl, off);
            if (lane >= off) incl += t;
        }
        if (lane == 63) wsum[wid] = incl;
        __syncthreads();
        if (wid == 0) {
            int ws = (lane < 16) ? wsum[lane] : 0;
            #pragma unroll
            for (int off = 1; off < 16; off <<= 1) {
                int t = __shfl_up(ws, off);
                if (lane >= off) ws += t;
            }
            if (lane < 16) wsum[lane] = ws;
        }
        __syncthreads();
        int carry = s_carry + ((wid > 0) ? wsum[wid - 1] : 0);
        int pre = carry + incl - s;   // exclusive prefix for this thread's chunk
        #pragma unroll
        for (int j = 0; j < CH; ++j) {
            int i = i0 + j;
            if (i < n) rowstart[i] = pre;
            pre += v[j];
        }
        __syncthreads();
        if (tid == 1023) s_carry = carry + incl;   // wave-15 inclusive total
        __syncthreads();
    }
    if (tid == 0) rowstart[n] = s_carry;
}

// ---------------- gemm1 body: S1[M,256] = x[M,512] @ W1T[256][512]^T ----------------
// Tile 128x256, 4 waves 2x2, RT=4 CT=8, BK=64. B via async16; A f32->bf16 cvt staging.
// Epilogue: two 128x128 column-half repacks through LDS (fits 48 KB staging array).

__device__ __forceinline__ void gemm1_body(const float* __restrict__ x,
                                           const u16* __restrict__ W1T,
                                           u16* __restrict__ S1, int M,
                                           int bid, u16* lds) {
    u16* As = lds;               // [128][64]
    u16* Bs = lds + 128 * 64;    // [256][64]

    const int tid  = threadIdx.x;
    const int wv   = tid >> 6, lane = tid & 63;
    const int lm   = lane & 15, quad = lane >> 4;
    const int wrow = wv >> 1, wcol = wv & 1;
    const int m0   = bid * 128;

    f32x4 acc[4][8];
    #pragma unroll
    for (int r = 0; r < 4; ++r)
        #pragma unroll
        for (int c = 0; c < 8; ++c) acc[r][c] = (f32x4){0.f, 0.f, 0.f, 0.f};

    for (int k0 = 0; k0 < NFEAT; k0 += 64) {
        // B tile: 256 rows x 64 k = 2048 16B chunks, 8 per thread
        #pragma unroll
        for (int i = 0; i < 8; ++i) {
            int c = i * 256 + tid;
            int n = c >> 3, ko = (c & 7) * 8;
            async16(W1T + (size_t)n * NFEAT + k0 + ko, Bs + c * 8);
        }
        // A tile: 128 rows x 64 k f32 -> bf16; thread = 32 elems (row=tid>>1)
        {
            int row = tid >> 1, ko = (tid & 1) * 32;
            int gr = m0 + row; if (gr > M - 1) gr = M - 1;
            const float4* gp = (const float4*)(x + (size_t)gr * NFEAT + k0 + ko);
            u32 p[16];
            #pragma unroll
            for (int q = 0; q < 8; ++q) {
                float4 f = gp[q];
                p[2 * q]     = pk2(f.x, f.y);
                p[2 * q + 1] = pk2(f.z, f.w);
            }
            u32* dp = (u32*)(As + row * 64 + ko);
            #pragma unroll
            for (int q = 0; q < 4; ++q) *(int4*)(dp + 4 * q) = *(int4*)&p[4 * q];
        }
        __syncthreads();   // drains async vmcnt + ds writes

        #pragma unroll
        for (int kk = 0; kk < 2; ++kk) {
            bf16x8 af[4], bfv[8];
            #pragma unroll
            for (int rt = 0; rt < 4; ++rt) {
                int row = wrow * 64 + rt * 16 + lm;
                af[rt] = *(const bf16x8*)(As + row * 64 + kk * 32 + quad * 8);
            }
            #pragma unroll
            for (int ct = 0; ct < 8; ++ct) {
                int n = wcol * 128 + ct * 16 + lm;
                bfv[ct] = *(const bf16x8*)(Bs + n * 64 + kk * 32 + quad * 8);
            }
            #pragma unroll
            for (int rt = 0; rt < 4; ++rt)
                #pragma unroll
                for (int ct = 0; ct < 8; ++ct)
                    acc[rt][ct] = __builtin_amdgcn_mfma_f32_16x16x32_bf16(
                        af[rt], bfv[ct], acc[rt][ct], 0, 0, 0);
        }
        __syncthreads();
    }

    // epilogue: two column halves (h = wcol) of 128x128 each
    for (int h = 0; h < 2; ++h) {
        __syncthreads();
        if (wcol == h) {
            #pragma unroll
            for (int rt = 0; rt < 4; ++rt)
                #pragma unroll
                for (int ct = 0; ct < 8; ++ct) {
                    int col = ct * 16 + lm;
                    #pragma unroll
                    for (int r = 0; r < 4; ++r) {
                        int row = wrow * 64 + rt * 16 + quad * 4 + r;  // C/D: row=quad*4+reg
                        lds[row * 128 + col] = f2bf(acc[rt][ct][r]);
                    }
                }
        }
        __syncthreads();
        #pragma unroll
        for (int i = 0; i < 8; ++i) {           // 128x128 bf16 = 2048 16B chunks
            int c = i * 256 + tid;
            int row = c >> 4, col8 = c & 15;
            if (m0 + row < M)
                *(int4*)(S1 + (size_t)(m0 + row) * NHID + h * 128 + col8 * 8) =
                    *(const int4*)(lds + c * 8);
        }
    }
}

// ---------------- fused gemm1 || scatter ----------------
// blocks [0,GB1): gemm1. blocks [GB1,GB1+SB): atomic-free CSR scatter,
// 8 contiguous edges/thread; position = rowstart[dst] + rank.

__global__ __launch_bounds__(256) void gemm1_scatter_kernel(
    const float* __restrict__ x, const u16* __restrict__ W1T, u16* __restrict__ S1,
    const int* __restrict__ esrc, const int* __restrict__ edst,
    const float* __restrict__ ew, const int* __restrict__ rowstart,
    const int* __restrict__ rank, u32* __restrict__ csr) {
    __shared__ __align__(16) u16 lds[(128 + 256) * 64];
    int b = blockIdx.x;
    if (b < GB1) {
        gemm1_body(x, W1T, S1, N_NODES, b, lds);
    } else {
        int e0 = ((b - GB1) * 256 + threadIdx.x) * 8;
        if (e0 < N_EDGES) {                       // 800000 % 8 == 0: full chunk
            int4 d0 = *(const int4*)(edst + e0),  d1 = *(const int4*)(edst + e0 + 4);
            int4 s0 = *(const int4*)(esrc + e0),  s1 = *(const int4*)(esrc + e0 + 4);
            float4 w0 = *(const float4*)(ew + e0), w1 = *(const float4*)(ew + e0 + 4);
            int4 r0 = *(const int4*)(rank + e0),  r1 = *(const int4*)(rank + e0 + 4);
            int d[8] = {d0.x, d0.y, d0.z, d0.w, d1.x, d1.y, d1.z, d1.w};
            int s[8] = {s0.x, s0.y, s0.z, s0.w, s1.x, s1.y, s1.z, s1.w};
            float w[8] = {w0.x, w0.y, w0.z, w0.w, w1.x, w1.y, w1.z, w1.w};
            int r[8] = {r0.x, r0.y, r0.z, r0.w, r1.x, r1.y, r1.z, r1.w};
            #pragma unroll
            for (int i = 0; i < 8; ++i) {
                int p = rowstart[d[i]] + r[i];
                csr[p] = (u32)s[i] | ((u32)f2bf(w[i]) << 16);   // cached: L2-merge
            }
        }
    }
}

// ---------------- mid: spmm1+bias+relu (H in LDS) + gemm2 -> S2 ----------------
// 512 threads (8 waves), 64 nodes/block. Phase 1: wave handles 8 nodes, 4 feats/lane,
// H rows written to LDS. Phase 2: S2[64x64] = Hs[64x256] @ W2Ts[64][256]^T,
// waves 4x2 (rows x cols), RT=1 CT=2, 8 kk halves. Epilogue repack through LDS.

__global__ __launch_bounds__(512) void mid_kernel(
    const u16* __restrict__ S1, const int* __restrict__ rowstart,
    const u32* __restrict__ csr, const float* __restrict__ b1,
    const u16* __restrict__ W2T, u16* __restrict__ S2, int n) {
    __shared__ __align__(16) u16 Hs[64 * 256];   // 32 KB
    __shared__ __align__(16) u16 Ws[64 * 256];   // 32 KB
    const int tid = threadIdx.x, wv = tid >> 6, lane = tid & 63;
    const int nb = blockIdx.x * 64;

    // stage W2T (32 KB = 2048 16B chunks, 4 per thread); drained by barrier below
    #pragma unroll
    for (int i = 0; i < 4; ++i) {
        int c = i * 512 + tid;
        async16(W2T + c * 8, Ws + c * 8);
    }

    // phase 1: aggregate + bias + relu into Hs
    for (int t = 0; t < 8; ++t) {
        int ln = wv * 8 + t;
        int node = nb + ln;
        float a0 = 0.f, a1 = 0.f, a2 = 0.f, a3 = 0.f;
        if (node < n) {
            int beg = rowstart[node], end = rowstart[node + 1];
            int j = beg;
            for (; j + 8 <= end; j += 8) {
                u32 e[8];
                #pragma unroll
                for (int i = 0; i < 8; ++i) e[i] = csr[j + i];
                ushort4 v[8];
                #pragma unroll
                for (int i = 0; i < 8; ++i)
                    v[i] = *(const ushort4*)(S1 + (size_t)(e[i] & 0xFFFFu) * NHID + lane * 4);
                #pragma unroll
                for (int i = 0; i < 8; ++i) {
                    float w = bf2f((u16)(e[i] >> 16));
                    a0 += w * bf2f(v[i].x); a1 += w * bf2f(v[i].y);
                    a2 += w * bf2f(v[i].z); a3 += w * bf2f(v[i].w);
                }
            }
            for (; j < end; ++j) {
                u32 e0 = csr[j];
                float w = bf2f((u16)(e0 >> 16));
                ushort4 v0 = *(const ushort4*)(S1 + (size_t)(e0 & 0xFFFFu) * NHID + lane * 4);
                a0 += w * bf2f(v0.x); a1 += w * bf2f(v0.y);
                a2 += w * bf2f(v0.z); a3 += w * bf2f(v0.w);
            }
            float4 bv = *(const float4*)(b1 + lane * 4);
            a0 = fmaxf(a0 + bv.x, 0.f);
            a1 = fmaxf(a1 + bv.y, 0.f);
            a2 = fmaxf(a2 + bv.z, 0.f);
            a3 = fmaxf(a3 + bv.w, 0.f);
        }
        ushort4 o;
        o.x = f2bf(a0); o.y = f2bf(a1); o.z = f2bf(a2); o.w = f2bf(a3);
        *(ushort4*)(Hs + ln * 256 + lane * 4) = o;
    }
    __syncthreads();   // Hs complete + W2T async drained

    // phase 2: 64x64x256 GEMM from LDS
    const int lm = lane & 15, quad = lane >> 4;
    const int wrow = wv & 3, wcol = wv >> 2;
    f32x4 acc[2];
    acc[0] = (f32x4){0.f, 0.f, 0.f, 0.f};
    acc[1] = (f32x4){0.f, 0.f, 0.f, 0.f};
    #pragma unroll
    for (int kk = 0; kk < 8; ++kk) {
        bf16x8 af = *(const bf16x8*)(Hs + (wrow * 16 + lm) * 256 + kk * 32 + quad * 8);
        #pragma unroll
        for (int ct = 0; ct < 2; ++ct) {
            bf16x8 bfv = *(const bf16x8*)(Ws + (wcol * 32 + ct * 16 + lm) * 256
                                          + kk * 32 + quad * 8);
            acc[ct] = __builtin_amdgcn_mfma_f32_16x16x32_bf16(af, bfv, acc[ct], 0, 0, 0);
        }
    }
    __syncthreads();   // done reading Hs; reuse for repack
    #pragma unroll
    for (int ct = 0; ct < 2; ++ct) {
        int col = wcol * 32 + ct * 16 + lm;
        #pragma unroll
        for (int r = 0; r < 4; ++r) {
            int row = wrow * 16 + quad * 4 + r;    // C/D: row=quad*4+reg
            Hs[row * 64 + col] = f2bf(acc[ct][r]);
        }
    }
    __syncthreads();
    {   // 64x64 bf16 = 512 16B chunks, 1 per thread
        int row = tid >> 3, col8 = tid & 7;
        if (nb + row < n)
            *(int4*)(S2 + (size_t)(nb + row) * NCLASS + col8 * 8) =
                *(const int4*)(Hs + tid * 8);
    }
}

// ---------------- SpMM2 + bias + log_softmax (one wave/node, 1 class/lane, 8-way) ----------------

__global__ __launch_bounds__(256) void spmm_bias_lsm_kernel(
    const u16* __restrict__ S, const int* __restrict__ rowstart,
    const u32* __restrict__ csr, const float* __restrict__ bias,
    float* __restrict__ out, int n) {
    int node = blockIdx.x * 4 + (threadIdx.x >> 6);
    if (node >= n) return;
    int lane = threadIdx.x & 63;
    int beg = rowstart[node], end = rowstart[node + 1];
    float acc = 0.f;
    int j = beg;
    for (; j + 8 <= end; j += 8) {
        u32 e[8];
        #pragma unroll
        for (int i = 0; i < 8; ++i) e[i] = csr[j + i];
        u16 v[8];
        #pragma unroll
        for (int i = 0; i < 8; ++i)
            v[i] = S[(size_t)(e[i] & 0xFFFFu) * NCLASS + lane];
        #pragma unroll
        for (int i = 0; i < 8; ++i)
            acc += bf2f((u16)(e[i] >> 16)) * bf2f(v[i]);
    }
    for (; j < end; ++j) {
        u32 e0 = csr[j];
        acc += bf2f((u16)(e0 >> 16)) * bf2f(S[(size_t)(e0 & 0xFFFFu) * NCLASS + lane]);
    }

    float x = acc + bias[lane];
    float m = x;
    #pragma unroll
    for (int off = 32; off > 0; off >>= 1) m = fmaxf(m, __shfl_xor(m, off));
    float e = expf(x - m);
    float ssum = e;
    #pragma unroll
    for (int off = 32; off > 0; off >>= 1) ssum += __shfl_xor(ssum, off);
    out[(size_t)node * NCLASS + lane] = x - m - logf(ssum);
}

// ---------------- launch ----------------

extern "C" void kernel_launch(void* const* d_in, const int* in_sizes, int n_in,
                              void* d_out, int out_size, void* d_ws, size_t ws_size,
                              hipStream_t stream) {
    const float* x  = (const float*)d_in[0];   // [50000,512]
    const float* W1 = (const float*)d_in[1];   // [512,256]
    const float* b1 = (const float*)d_in[2];   // [256]
    const float* W2 = (const float*)d_in[3];   // [256,64]
    const float* b2 = (const float*)d_in[4];   // [64]
    const float* ew = (const float*)d_in[5];   // [800000]
    const int* esrc = (const int*)d_in[6];
    const int* edst = (const int*)d_in[7];
    float* out = (float*)d_out;                // [50000,64]

    char* ws = (char*)d_ws;
    size_t off = 0;
    auto take = [&](size_t bytes) -> void* {
        off = (off + 255) & ~(size_t)255;
        void* p = ws + off;
        off += bytes;
        return p;
    };
    u16* S1       = (u16*)take((size_t)N_NODES * NHID * 2);    // 25.6 MB
    u16* S2       = (u16*)take((size_t)N_NODES * NCLASS * 2);  // 6.4 MB
    u16* W1T      = (u16*)take((size_t)NHID * NFEAT * 2);      // [256][512]
    u16* W2T      = (u16*)take((size_t)NCLASS * NHID * 2);     // [64][256]
    int* deg      = (int*)take((size_t)DEG_PAD * 4);
    int* rowstart = (int*)take((size_t)(N_NODES + 1) * 4);
    int* rank     = (int*)take((size_t)N_EDGES * 4);           // 3.2 MB
    u32* csr      = (u32*)take((size_t)N_EDGES * 4);           // 3.2 MB packed
    (void)ws_size; (void)in_sizes; (void)n_in; (void)out_size;

    hipMemsetAsync(deg, 0, (size_t)DEG_PAD * 4, stream);
    prep_kernel<<<967, 256, 0, stream>>>(W1, W1T, W2, W2T, edst, deg, rank);
    scan_kernel<<<1, 1024, 0, stream>>>(deg, rowstart, N_NODES);
    gemm1_scatter_kernel<<<GB1 + SB, 256, 0, stream>>>(x, W1T, S1, esrc, edst, ew,
                                                       rowstart, rank, csr);
    mid_kernel<<<(N_NODES + 63) / 64, 512, 0, stream>>>(
        S1, rowstart, csr, b1, W2T, S2, N_NODES);
    spmm_bias_lsm_kernel<<<(N_NODES + 3) / 4, 256, 0, stream>>>(
        S2, rowstart, csr, b2, out, N_NODES);
}

// Round 8
// 372.749 us; speedup vs baseline: 1.0822x; 1.0822x over previous
//
#include <hip/hip_runtime.h>
#include <cstdint>

// GCN forward on MI355X (gfx950). f32 in/out; bf16 MFMA with fp32 accum;
// bf16 intermediates; 4-byte packed CSR entries (src:u16 | weight:bf16).
// Chain (7): memset deg -> prep(transposes+count+rank) -> scan
//   -> [gemm1(128x256 tile) || scatter] -> spmm1+bias+relu -> gemm2
//   -> spmm2+bias+log_softmax.
// Round 8: reverted round-7 mid fusion (TLP collapse: 16 waves/CU + 8-node serial
// loop per wave made the gather phase 2x slower); kept 128x256 gemm1 tile.

typedef unsigned short u16;
typedef unsigned int u32;
typedef __attribute__((ext_vector_type(8))) short bf16x8;
typedef __attribute__((ext_vector_type(4))) float f32x4;

#define N_NODES 50000
#define N_EDGES 800000
#define NFEAT 512
#define NHID 256
#define NCLASS 64
#define DEG_PAD 65536     // scan reads unguarded int4; zero-padded

#define GB1 391           // gemm1 blocks: ceil(50000/128)
#define SB  391           // scatter blocks: ceil(800000/2048)

__device__ __forceinline__ float bf2f(u16 h) {
    union { u32 u; float f; } c; c.u = ((u32)h) << 16; return c.f;
}
__device__ __forceinline__ u16 f2bf(float f) {
    union { float f; u32 u; } c; c.f = f;
    u32 u = c.u;
    return (u16)((u + 0x7fffu + ((u >> 16) & 1u)) >> 16);   // RNE
}
__device__ __forceinline__ u32 pk2(float a, float b) {
    return (u32)f2bf(a) | ((u32)f2bf(b) << 16);
}

// async global->LDS, 16B per lane; LDS dest = wave-uniform base + lane*16.
__device__ __forceinline__ void async16(const void* g, void* l) {
    __builtin_amdgcn_global_load_lds(
        (const __attribute__((address_space(1))) void*)(uintptr_t)g,
        (__attribute__((address_space(3))) void*)(uintptr_t)l, 16, 0, 0);
}

// ---------------- prep: W1/W2 transpose+cvt + degree count + rank ----------------
// blocks [0,512): W1T, [512,576): W2T, [576,967): count 8 edges/thread (int4 loads)

__global__ __launch_bounds__(256) void prep_kernel(
    const float* __restrict__ W1, u16* __restrict__ W1T,
    const float* __restrict__ W2, u16* __restrict__ W2T,
    const int* __restrict__ edst, int* __restrict__ deg, int* __restrict__ rank) {
    int b = blockIdx.x;
    if (b < 512) {
        int idx = b * 256 + threadIdx.x;           // W1T[256][512]
        int n = idx >> 9, k = idx & 511;
        W1T[idx] = f2bf(W1[(size_t)k * NHID + n]);
    } else if (b < 576) {
        int idx = (b - 512) * 256 + threadIdx.x;   // W2T[64][256]
        int n = idx >> 8, k = idx & 255;
        W2T[idx] = f2bf(W2[(size_t)k * NCLASS + n]);
    } else {
        int e0 = ((b - 576) * 256 + threadIdx.x) * 8;
        if (e0 < N_EDGES) {                        // 800000 % 8 == 0: full chunk
            int4 d0 = *(const int4*)(edst + e0);
            int4 d1 = *(const int4*)(edst + e0 + 4);
            int d[8] = {d0.x, d0.y, d0.z, d0.w, d1.x, d1.y, d1.z, d1.w};
            int r[8];
            #pragma unroll
            for (int i = 0; i < 8; ++i) r[i] = atomicAdd(&deg[d[i]], 1);
            *(int4*)(rank + e0)     = make_int4(r[0], r[1], r[2], r[3]);
            *(int4*)(rank + e0 + 4) = make_int4(r[4], r[5], r[6], r[7]);
        }
    }
}

// ---------------- scan: deg[0..n) -> rowstart[0..n] ----------------

__global__ __launch_bounds__(1024) void scan_kernel(const int* __restrict__ deg,
                                                    int* __restrict__ rowstart, int n) {
    __shared__ int wsum[16];
    __shared__ int s_carry;
    const int tid = threadIdx.x;
    const int lane = tid & 63, wid = tid >> 6;
    if (tid == 0) s_carry = 0;
    __syncthreads();
    const int CH = 16;
    for (int base = 0; base < DEG_PAD; base += 1024 * CH) {   // 4 iterations
        int i0 = base + tid * CH;
        int v[CH];
        #pragma unroll
        for (int q = 0; q < 4; ++q)
            *(int4*)&v[q * 4] = *(const int4*)(deg + i0 + q * 4);
        int s = 0;
        #pragma unroll
        for (int j = 0; j < CH; ++j) s += v[j];
        int incl = s;
        #pragma unroll
        for (int off = 1; off < 64; off <<= 1) {
            int t = __shfl_up(incl, off);
            if (lane >= off) incl += t;
        }
        if (lane == 63) wsum[wid] = incl;
        __syncthreads();
        if (wid == 0) {
            int ws = (lane < 16) ? wsum[lane] : 0;
            #pragma unroll
            for (int off = 1; off < 16; off <<= 1) {
                int t = __shfl_up(ws, off);
                if (lane >= off) ws += t;
            }
            if (lane < 16) wsum[lane] = ws;
        }
        __syncthreads();
        int carry = s_carry + ((wid > 0) ? wsum[wid - 1] : 0);
        int pre = carry + incl - s;   // exclusive prefix for this thread's chunk
        #pragma unroll
        for (int j = 0; j < CH; ++j) {
            int i = i0 + j;
            if (i < n) rowstart[i] = pre;
            pre += v[j];
        }
        __syncthreads();
        if (tid == 1023) s_carry = carry + incl;   // wave-15 inclusive total
        __syncthreads();
    }
    if (tid == 0) rowstart[n] = s_carry;
}

// ---------------- gemm1 body: S1[M,256] = x[M,512] @ W1T[256][512]^T ----------------
// Tile 128x256, 4 waves 2x2, RT=4 CT=8, BK=64. B via async16; A f32->bf16 cvt staging.
// Epilogue: two 128x128 column-half repacks through LDS.

__device__ __forceinline__ void gemm1_body(const float* __restrict__ x,
                                           const u16* __restrict__ W1T,
                                           u16* __restrict__ S1, int M,
                                           int bid, u16* lds) {
    u16* As = lds;               // [128][64]
    u16* Bs = lds + 128 * 64;    // [256][64]

    const int tid  = threadIdx.x;
    const int wv   = tid >> 6, lane = tid & 63;
    const int lm   = lane & 15, quad = lane >> 4;
    const int wrow = wv >> 1, wcol = wv & 1;
    const int m0   = bid * 128;

    f32x4 acc[4][8];
    #pragma unroll
    for (int r = 0; r < 4; ++r)
        #pragma unroll
        for (int c = 0; c < 8; ++c) acc[r][c] = (f32x4){0.f, 0.f, 0.f, 0.f};

    for (int k0 = 0; k0 < NFEAT; k0 += 64) {
        // B tile: 256 rows x 64 k = 2048 16B chunks, 8 per thread
        #pragma unroll
        for (int i = 0; i < 8; ++i) {
            int c = i * 256 + tid;
            int n = c >> 3, ko = (c & 7) * 8;
            async16(W1T + (size_t)n * NFEAT + k0 + ko, Bs + c * 8);
        }
        // A tile: 128 rows x 64 k f32 -> bf16; thread = 32 elems (row=tid>>1)
        {
            int row = tid >> 1, ko = (tid & 1) * 32;
            int gr = m0 + row; if (gr > M - 1) gr = M - 1;
            const float4* gp = (const float4*)(x + (size_t)gr * NFEAT + k0 + ko);
            u32 p[16];
            #pragma unroll
            for (int q = 0; q < 8; ++q) {
                float4 f = gp[q];
                p[2 * q]     = pk2(f.x, f.y);
                p[2 * q + 1] = pk2(f.z, f.w);
            }
            u32* dp = (u32*)(As + row * 64 + ko);
            #pragma unroll
            for (int q = 0; q < 4; ++q) *(int4*)(dp + 4 * q) = *(int4*)&p[4 * q];
        }
        __syncthreads();   // drains async vmcnt + ds writes

        #pragma unroll
        for (int kk = 0; kk < 2; ++kk) {
            bf16x8 af[4], bfv[8];
            #pragma unroll
            for (int rt = 0; rt < 4; ++rt) {
                int row = wrow * 64 + rt * 16 + lm;
                af[rt] = *(const bf16x8*)(As + row * 64 + kk * 32 + quad * 8);
            }
            #pragma unroll
            for (int ct = 0; ct < 8; ++ct) {
                int n = wcol * 128 + ct * 16 + lm;
                bfv[ct] = *(const bf16x8*)(Bs + n * 64 + kk * 32 + quad * 8);
            }
            #pragma unroll
            for (int rt = 0; rt < 4; ++rt)
                #pragma unroll
                for (int ct = 0; ct < 8; ++ct)
                    acc[rt][ct] = __builtin_amdgcn_mfma_f32_16x16x32_bf16(
                        af[rt], bfv[ct], acc[rt][ct], 0, 0, 0);
        }
        __syncthreads();
    }

    // epilogue: two column halves (h = wcol) of 128x128 each
    for (int h = 0; h < 2; ++h) {
        __syncthreads();
        if (wcol == h) {
            #pragma unroll
            for (int rt = 0; rt < 4; ++rt)
                #pragma unroll
                for (int ct = 0; ct < 8; ++ct) {
                    int col = ct * 16 + lm;
                    #pragma unroll
                    for (int r = 0; r < 4; ++r) {
                        int row = wrow * 64 + rt * 16 + quad * 4 + r;  // C/D: row=quad*4+reg
                        lds[row * 128 + col] = f2bf(acc[rt][ct][r]);
                    }
                }
        }
        __syncthreads();
        #pragma unroll
        for (int i = 0; i < 8; ++i) {           // 128x128 bf16 = 2048 16B chunks
            int c = i * 256 + tid;
            int row = c >> 4, col8 = c & 15;
            if (m0 + row < M)
                *(int4*)(S1 + (size_t)(m0 + row) * NHID + h * 128 + col8 * 8) =
                    *(const int4*)(lds + c * 8);
        }
    }
}

// ---------------- fused gemm1 || scatter ----------------
// blocks [0,GB1): gemm1. blocks [GB1,GB1+SB): atomic-free CSR scatter,
// 8 contiguous edges/thread; position = rowstart[dst] + rank.

__global__ __launch_bounds__(256) void gemm1_scatter_kernel(
    const float* __restrict__ x, const u16* __restrict__ W1T, u16* __restrict__ S1,
    const int* __restrict__ esrc, const int* __restrict__ edst,
    const float* __restrict__ ew, const int* __restrict__ rowstart,
    const int* __restrict__ rank, u32* __restrict__ csr) {
    __shared__ __align__(16) u16 lds[(128 + 256) * 64];
    int b = blockIdx.x;
    if (b < GB1) {
        gemm1_body(x, W1T, S1, N_NODES, b, lds);
    } else {
        int e0 = ((b - GB1) * 256 + threadIdx.x) * 8;
        if (e0 < N_EDGES) {                       // 800000 % 8 == 0: full chunk
            int4 d0 = *(const int4*)(edst + e0),  d1 = *(const int4*)(edst + e0 + 4);
            int4 s0 = *(const int4*)(esrc + e0),  s1 = *(const int4*)(esrc + e0 + 4);
            float4 w0 = *(const float4*)(ew + e0), w1 = *(const float4*)(ew + e0 + 4);
            int4 r0 = *(const int4*)(rank + e0),  r1 = *(const int4*)(rank + e0 + 4);
            int d[8] = {d0.x, d0.y, d0.z, d0.w, d1.x, d1.y, d1.z, d1.w};
            int s[8] = {s0.x, s0.y, s0.z, s0.w, s1.x, s1.y, s1.z, s1.w};
            float w[8] = {w0.x, w0.y, w0.z, w0.w, w1.x, w1.y, w1.z, w1.w};
            int r[8] = {r0.x, r0.y, r0.z, r0.w, r1.x, r1.y, r1.z, r1.w};
            #pragma unroll
            for (int i = 0; i < 8; ++i) {
                int p = rowstart[d[i]] + r[i];
                csr[p] = (u32)s[i] | ((u32)f2bf(w[i]) << 16);   // cached: L2-merge
            }
        }
    }
}

// ---------------- gemm2: S2[M,64] = H[M,256] @ W2T[64][256]^T ----------------
// Tile 128x64, 4 waves 2x2, RT=4 CT=2, BK=64; both operands via async16.

__global__ __launch_bounds__(256) void gemm2_kernel(const u16* __restrict__ H,
                                                    const u16* __restrict__ W2T,
                                                    u16* __restrict__ S2, int M) {
    __shared__ __align__(16) u16 lds[(128 + 64) * 64];
    u16* As = lds;             // [128][64]
    u16* Bs = lds + 128 * 64;  // [64][64]
    const int tid  = threadIdx.x;
    const int wv   = tid >> 6, lane = tid & 63;
    const int lm   = lane & 15, quad = lane >> 4;
    const int wrow = wv >> 1, wcol = wv & 1;
    const int m0   = blockIdx.x * 128;

    f32x4 acc[4][2];
    #pragma unroll
    for (int r = 0; r < 4; ++r)
        #pragma unroll
        for (int c = 0; c < 2; ++c) acc[r][c] = (f32x4){0.f, 0.f, 0.f, 0.f};

    for (int k0 = 0; k0 < NHID; k0 += 64) {
        #pragma unroll
        for (int i = 0; i < 2; ++i) {            // B: 64x64 = 512 chunks
            int c = i * 256 + tid;
            int n = c >> 3, ko = (c & 7) * 8;
            async16(W2T + (size_t)n * NHID + k0 + ko, Bs + c * 8);
        }
        #pragma unroll
        for (int i = 0; i < 4; ++i) {            // A: 128x64 = 1024 chunks
            int c = i * 256 + tid;
            int row = c >> 3, ko = (c & 7) * 8;
            int gr = m0 + row; if (gr > M - 1) gr = M - 1;
            async16(H + (size_t)gr * NHID + k0 + ko, As + c * 8);
        }
        __syncthreads();

        #pragma unroll
        for (int kk = 0; kk < 2; ++kk) {
            bf16x8 af[4], bfv[2];
            #pragma unroll
            for (int rt = 0; rt < 4; ++rt) {
                int row = wrow * 64 + rt * 16 + lm;
                af[rt] = *(const bf16x8*)(As + row * 64 + kk * 32 + quad * 8);
            }
            #pragma unroll
            for (int ct = 0; ct < 2; ++ct) {
                int n = wcol * 32 + ct * 16 + lm;
                bfv[ct] = *(const bf16x8*)(Bs + n * 64 + kk * 32 + quad * 8);
            }
            #pragma unroll
            for (int rt = 0; rt < 4; ++rt)
                #pragma unroll
                for (int ct = 0; ct < 2; ++ct)
                    acc[rt][ct] = __builtin_amdgcn_mfma_f32_16x16x32_bf16(
                        af[rt], bfv[ct], acc[rt][ct], 0, 0, 0);
        }
        __syncthreads();
    }

    // epilogue: [128][64] bf16 through LDS, coalesced 16B stores
    #pragma unroll
    for (int rt = 0; rt < 4; ++rt)
        #pragma unroll
        for (int ct = 0; ct < 2; ++ct) {
            int col = wcol * 32 + ct * 16 + lm;
            #pragma unroll
            for (int r = 0; r < 4; ++r) {
                int row = wrow * 64 + rt * 16 + quad * 4 + r;   // C/D: row=quad*4+reg
                lds[row * 64 + col] = f2bf(acc[rt][ct][r]);
            }
        }
    __syncthreads();
    #pragma unroll
    for (int i = 0; i < 4; ++i) {               // 128x64 bf16 = 1024 16B chunks
        int c = i * 256 + tid;
        int row = c >> 3, col8 = c & 7;
        if (m0 + row < M)
            *(int4*)(S2 + (size_t)(m0 + row) * NCLASS + col8 * 8) =
                *(const int4*)(lds + c * 8);
    }
}

// ---------------- SpMM1 + bias + ReLU (one wave/node, 4 feats/lane, 8-way unroll) ----------------

__global__ __launch_bounds__(256) void spmm_bias_relu_kernel(
    const u16* __restrict__ S, const int* __restrict__ rowstart,
    const u32* __restrict__ csr, const float* __restrict__ bias,
    u16* __restrict__ H, int n) {
    int node = blockIdx.x * 4 + (threadIdx.x >> 6);
    if (node >= n) return;
    int lane = threadIdx.x & 63;
    int beg = rowstart[node], end = rowstart[node + 1];
    float a0 = 0.f, a1 = 0.f, a2 = 0.f, a3 = 0.f;
    int j = beg;
    for (; j + 8 <= end; j += 8) {           // 8 outstanding gathers
        u32 e[8];
        #pragma unroll
        for (int i = 0; i < 8; ++i) e[i] = csr[j + i];   // uniform addr: s_load path
        ushort4 v[8];
        #pragma unroll
        for (int i = 0; i < 8; ++i)
            v[i] = *(const ushort4*)(S + (size_t)(e[i] & 0xFFFFu) * NHID + lane * 4);
        #pragma unroll
        for (int i = 0; i < 8; ++i) {
            float w = bf2f((u16)(e[i] >> 16));
            a0 += w * bf2f(v[i].x); a1 += w * bf2f(v[i].y);
            a2 += w * bf2f(v[i].z); a3 += w * bf2f(v[i].w);
        }
    }
    for (; j < end; ++j) {
        u32 e0 = csr[j];
        float w = bf2f((u16)(e0 >> 16));
        ushort4 v0 = *(const ushort4*)(S + (size_t)(e0 & 0xFFFFu) * NHID + lane * 4);
        a0 += w * bf2f(v0.x); a1 += w * bf2f(v0.y);
        a2 += w * bf2f(v0.z); a3 += w * bf2f(v0.w);
    }
    float4 bv = *(const float4*)(bias + lane * 4);
    a0 = fmaxf(a0 + bv.x, 0.f);
    a1 = fmaxf(a1 + bv.y, 0.f);
    a2 = fmaxf(a2 + bv.z, 0.f);
    a3 = fmaxf(a3 + bv.w, 0.f);
    ushort4 o;
    o.x = f2bf(a0); o.y = f2bf(a1); o.z = f2bf(a2); o.w = f2bf(a3);
    *(ushort4*)(H + (size_t)node * NHID + lane * 4) = o;
}

// ---------------- SpMM2 + bias + log_softmax (one wave/node, 1 class/lane, 8-way) ----------------

__global__ __launch_bounds__(256) void spmm_bias_lsm_kernel(
    const u16* __restrict__ S, const int* __restrict__ rowstart,
    const u32* __restrict__ csr, const float* __restrict__ bias,
    float* __restrict__ out, int n) {
    int node = blockIdx.x * 4 + (threadIdx.x >> 6);
    if (node >= n) return;
    int lane = threadIdx.x & 63;
    int beg = rowstart[node], end = rowstart[node + 1];
    float acc = 0.f;
    int j = beg;
    for (; j + 8 <= end; j += 8) {
        u32 e[8];
        #pragma unroll
        for (int i = 0; i < 8; ++i) e[i] = csr[j + i];
        u16 v[8];
        #pragma unroll
        for (int i = 0; i < 8; ++i)
            v[i] = S[(size_t)(e[i] & 0xFFFFu) * NCLASS + lane];
        #pragma unroll
        for (int i = 0; i < 8; ++i)
            acc += bf2f((u16)(e[i] >> 16)) * bf2f(v[i]);
    }
    for (; j < end; ++j) {
        u32 e0 = csr[j];
        acc += bf2f((u16)(e0 >> 16)) * bf2f(S[(size_t)(e0 & 0xFFFFu) * NCLASS + lane]);
    }

    float x = acc + bias[lane];
    float m = x;
    #pragma unroll
    for (int off = 32; off > 0; off >>= 1) m = fmaxf(m, __shfl_xor(m, off));
    float e = expf(x - m);
    float ssum = e;
    #pragma unroll
    for (int off = 32; off > 0; off >>= 1) ssum += __shfl_xor(ssum, off);
    out[(size_t)node * NCLASS + lane] = x - m - logf(ssum);
}

// ---------------- launch ----------------

extern "C" void kernel_launch(void* const* d_in, const int* in_sizes, int n_in,
                              void* d_out, int out_size, void* d_ws, size_t ws_size,
                              hipStream_t stream) {
    const float* x  = (const float*)d_in[0];   // [50000,512]
    const float* W1 = (const float*)d_in[1];   // [512,256]
    const float* b1 = (const float*)d_in[2];   // [256]
    const float* W2 = (const float*)d_in[3];   // [256,64]
    const float* b2 = (const float*)d_in[4];   // [64]
    const float* ew = (const float*)d_in[5];   // [800000]
    const int* esrc = (const int*)d_in[6];
    const int* edst = (const int*)d_in[7];
    float* out = (float*)d_out;                // [50000,64]

    char* ws = (char*)d_ws;
    size_t off = 0;
    auto take = [&](size_t bytes) -> void* {
        off = (off + 255) & ~(size_t)255;
        void* p = ws + off;
        off += bytes;
        return p;
    };
    u16* S1       = (u16*)take((size_t)N_NODES * NHID * 2);    // 25.6 MB
    u16* H        = (u16*)take((size_t)N_NODES * NHID * 2);    // 25.6 MB
    u16* S2       = (u16*)take((size_t)N_NODES * NCLASS * 2);  // 6.4 MB
    u16* W1T      = (u16*)take((size_t)NHID * NFEAT * 2);      // [256][512]
    u16* W2T      = (u16*)take((size_t)NCLASS * NHID * 2);     // [64][256]
    int* deg      = (int*)take((size_t)DEG_PAD * 4);
    int* rowstart = (int*)take((size_t)(N_NODES + 1) * 4);
    int* rank     = (int*)take((size_t)N_EDGES * 4);           // 3.2 MB
    u32* csr      = (u32*)take((size_t)N_EDGES * 4);           // 3.2 MB packed
    (void)ws_size; (void)in_sizes; (void)n_in; (void)out_size;

    hipMemsetAsync(deg, 0, (size_t)DEG_PAD * 4, stream);
    prep_kernel<<<967, 256, 0, stream>>>(W1, W1T, W2, W2T, edst, deg, rank);
    scan_kernel<<<1, 1024, 0, stream>>>(deg, rowstart, N_NODES);
    gemm1_scatter_kernel<<<GB1 + SB, 256, 0, stream>>>(x, W1T, S1, esrc, edst, ew,
                                                       rowstart, rank, csr);
    spmm_bias_relu_kernel<<<(N_NODES + 3) / 4, 256, 0, stream>>>(
        S1, rowstart, csr, b1, H, N_NODES);
    gemm2_kernel<<<(N_NODES + 127) / 128, 256, 0, stream>>>(H, W2T, S2, N_NODES);
    spmm_bias_lsm_kernel<<<(N_NODES + 3) / 4, 256, 0, stream>>>(
        S2, rowstart, csr, b2, out, N_NODES);
}

// Round 9
// 348.058 us; speedup vs baseline: 1.1590x; 1.0709x over previous
//
#include <hip/hip_runtime.h>
#include <cstdint>

// GCN forward on MI355X (gfx950). f32 in/out; bf16 MFMA with fp32 accum;
// bf16 intermediates; 4-byte packed CSR entries (src:u16 | weight:bf16).
// Chain (7): memset deg -> prep(transposes+count+rank) -> [scan || x->bf16 cvt]
//   -> [gemm1(64x256, pure async) || scatter] -> spmm1+bias+relu -> gemm2
//   -> spmm2+bias+log_softmax.
// Round 9: reverted MT=128 gemm1 (occupancy 9%, +21 us regression); x pre-converted
// to bf16 in the scan dispatch's idle CUs; gemm1 A-path now global_load_lds.

typedef unsigned short u16;
typedef unsigned int u32;
typedef __attribute__((ext_vector_type(8))) short bf16x8;
typedef __attribute__((ext_vector_type(4))) float f32x4;

#define N_NODES 50000
#define N_EDGES 800000
#define NFEAT 512
#define NHID 256
#define NCLASS 64
#define DEG_PAD 65536     // scan reads unguarded int4; zero-padded
#define XELEMS (N_NODES * NFEAT)   // 25.6M

#define GB1 782           // gemm1 blocks: ceil(50000/64)
#define SB  391           // scatter blocks: ceil(800000/2048)
#define XCB 1563          // xcvt blocks: ceil(25.6M / 16384)

__device__ __forceinline__ float bf2f(u16 h) {
    union { u32 u; float f; } c; c.u = ((u32)h) << 16; return c.f;
}
__device__ __forceinline__ u16 f2bf(float f) {
    union { float f; u32 u; } c; c.f = f;
    u32 u = c.u;
    return (u16)((u + 0x7fffu + ((u >> 16) & 1u)) >> 16);   // RNE
}
__device__ __forceinline__ u32 pk2(float a, float b) {
    return (u32)f2bf(a) | ((u32)f2bf(b) << 16);
}

// async global->LDS, 16B per lane; LDS dest = wave-uniform base + lane*16.
__device__ __forceinline__ void async16(const void* g, void* l) {
    __builtin_amdgcn_global_load_lds(
        (const __attribute__((address_space(1))) void*)(uintptr_t)g,
        (__attribute__((address_space(3))) void*)(uintptr_t)l, 16, 0, 0);
}

// ---------------- prep: W1/W2 transpose+cvt + degree count + rank ----------------
// blocks [0,512): W1T, [512,576): W2T, [576,967): count 8 edges/thread (int4 loads)

__global__ __launch_bounds__(256) void prep_kernel(
    const float* __restrict__ W1, u16* __restrict__ W1T,
    const float* __restrict__ W2, u16* __restrict__ W2T,
    const int* __restrict__ edst, int* __restrict__ deg, int* __restrict__ rank) {
    int b = blockIdx.x;
    if (b < 512) {
        int idx = b * 256 + threadIdx.x;           // W1T[256][512]
        int n = idx >> 9, k = idx & 511;
        W1T[idx] = f2bf(W1[(size_t)k * NHID + n]);
    } else if (b < 576) {
        int idx = (b - 512) * 256 + threadIdx.x;   // W2T[64][256]
        int n = idx >> 8, k = idx & 255;
        W2T[idx] = f2bf(W2[(size_t)k * NCLASS + n]);
    } else {
        int e0 = ((b - 576) * 256 + threadIdx.x) * 8;
        if (e0 < N_EDGES) {                        // 800000 % 8 == 0: full chunk
            int4 d0 = *(const int4*)(edst + e0);
            int4 d1 = *(const int4*)(edst + e0 + 4);
            int d[8] = {d0.x, d0.y, d0.z, d0.w, d1.x, d1.y, d1.z, d1.w};
            int r[8];
            #pragma unroll
            for (int i = 0; i < 8; ++i) r[i] = atomicAdd(&deg[d[i]], 1);
            *(int4*)(rank + e0)     = make_int4(r[0], r[1], r[2], r[3]);
            *(int4*)(rank + e0 + 4) = make_int4(r[4], r[5], r[6], r[7]);
        }
    }
}

// ---------------- scan (block 0) || x->bf16 conversion (blocks 1..XCB) ----------------

__global__ __launch_bounds__(1024) void scan_xcvt_kernel(
    const int* __restrict__ deg, int* __restrict__ rowstart, int n,
    const float* __restrict__ x, u16* __restrict__ xb) {
    if (blockIdx.x != 0) {
        // xcvt: 1024 threads x 16 elems = 16384 elems/block
        int base = (blockIdx.x - 1) * 16384 + threadIdx.x * 16;
        if (base < XELEMS) {
            const float4* gp = (const float4*)(x + base);
            float4 f0 = gp[0], f1 = gp[1], f2 = gp[2], f3 = gp[3];
            u32 p[8] = {pk2(f0.x, f0.y), pk2(f0.z, f0.w), pk2(f1.x, f1.y), pk2(f1.z, f1.w),
                        pk2(f2.x, f2.y), pk2(f2.z, f2.w), pk2(f3.x, f3.y), pk2(f3.z, f3.w)};
            u32* dp = (u32*)(xb + base);
            *(int4*)dp       = *(int4*)&p[0];
            *(int4*)(dp + 4) = *(int4*)&p[4];
        }
        return;
    }
    __shared__ int wsum[16];
    __shared__ int s_carry;
    const int tid = threadIdx.x;
    const int lane = tid & 63, wid = tid >> 6;
    if (tid == 0) s_carry = 0;
    __syncthreads();
    const int CH = 16;
    for (int base = 0; base < DEG_PAD; base += 1024 * CH) {   // 4 iterations
        int i0 = base + tid * CH;
        int v[CH];
        #pragma unroll
        for (int q = 0; q < 4; ++q)
            *(int4*)&v[q * 4] = *(const int4*)(deg + i0 + q * 4);
        int s = 0;
        #pragma unroll
        for (int j = 0; j < CH; ++j) s += v[j];
        int incl = s;
        #pragma unroll
        for (int off = 1; off < 64; off <<= 1) {
            int t = __shfl_up(incl, off);
            if (lane >= off) incl += t;
        }
        if (lane == 63) wsum[wid] = incl;
        __syncthreads();
        if (wid == 0) {
            int ws = (lane < 16) ? wsum[lane] : 0;
            #pragma unroll
            for (int off = 1; off < 16; off <<= 1) {
                int t = __shfl_up(ws, off);
                if (lane >= off) ws += t;
            }
            if (lane < 16) wsum[lane] = ws;
        }
        __syncthreads();
        int carry = s_carry + ((wid > 0) ? wsum[wid - 1] : 0);
        int pre = carry + incl - s;   // exclusive prefix for this thread's chunk
        #pragma unroll
        for (int j = 0; j < CH; ++j) {
            int i = i0 + j;
            if (i < n) rowstart[i] = pre;
            pre += v[j];
        }
        __syncthreads();
        if (tid == 1023) s_carry = carry + incl;   // wave-15 inclusive total
        __syncthreads();
    }
    if (tid == 0) rowstart[n] = s_carry;
}

// ---------------- shared GEMM body: C[M,NT] = A[M,K] @ BT[NT][K]^T ----------------
// A bf16 [M][K], BT bf16 [NT][K]; both staged via global_load_lds dwordx4.
// 4 waves WROWSxWCOLS, BK=64 (2 k-halves). Epilogue repacks C through LDS.

template <int MT, int NT, int WCOLS, int K>
__device__ __forceinline__ void gemm_body(const u16* __restrict__ A,
                                          const u16* __restrict__ BT,
                                          u16* __restrict__ C, int M,
                                          int bid, u16* lds) {
    constexpr int WROWS = 4 / WCOLS;
    constexpr int RT = MT / (16 * WROWS);
    constexpr int CT = NT / (16 * WCOLS);
    u16* As = lds;             // [MT][64] contiguous
    u16* Bs = lds + MT * 64;   // [NT][64] contiguous (B^T: row n, k-contig)

    const int tid  = threadIdx.x;
    const int wv   = tid >> 6, lane = tid & 63;
    const int lm   = lane & 15, quad = lane >> 4;
    const int wrow = wv / WCOLS, wcol = wv % WCOLS;
    const int m0   = bid * MT;

    f32x4 acc[RT][CT];
    #pragma unroll
    for (int r = 0; r < RT; ++r)
        #pragma unroll
        for (int c = 0; c < CT; ++c) acc[r][c] = (f32x4){0.f, 0.f, 0.f, 0.f};

    for (int k0 = 0; k0 < K; k0 += 64) {
        #pragma unroll
        for (int i = 0; i < NT / 32; ++i) {
            int c = i * 256 + tid;
            int n = c >> 3, ko = (c & 7) * 8;
            async16(BT + (size_t)n * K + k0 + ko, Bs + c * 8);
        }
        #pragma unroll
        for (int i = 0; i < MT / 32; ++i) {
            int c = i * 256 + tid;
            int row = c >> 3, ko = (c & 7) * 8;
            int gr = m0 + row; if (gr > M - 1) gr = M - 1;
            async16(A + (size_t)gr * K + k0 + ko, As + c * 8);
        }
        __syncthreads();   // drains async vmcnt

        #pragma unroll
        for (int kk = 0; kk < 2; ++kk) {
            bf16x8 af[RT], bfv[CT];
            #pragma unroll
            for (int rt = 0; rt < RT; ++rt) {
                int row = wrow * (RT * 16) + rt * 16 + lm;
                af[rt] = *(const bf16x8*)(As + row * 64 + kk * 32 + quad * 8);
            }
            #pragma unroll
            for (int ct = 0; ct < CT; ++ct) {
                int n = wcol * CT * 16 + ct * 16 + lm;
                bfv[ct] = *(const bf16x8*)(Bs + n * 64 + kk * 32 + quad * 8);
            }
            #pragma unroll
            for (int rt = 0; rt < RT; ++rt)
                #pragma unroll
                for (int ct = 0; ct < CT; ++ct)
                    acc[rt][ct] = __builtin_amdgcn_mfma_f32_16x16x32_bf16(
                        af[rt], bfv[ct], acc[rt][ct], 0, 0, 0);
        }
        __syncthreads();
    }

    #pragma unroll
    for (int rt = 0; rt < RT; ++rt)
        #pragma unroll
        for (int ct = 0; ct < CT; ++ct) {
            int col = wcol * CT * 16 + ct * 16 + lm;
            #pragma unroll
            for (int r = 0; r < 4; ++r) {
                int row = wrow * (RT * 16) + rt * 16 + quad * 4 + r;  // C/D: row=quad*4+reg
                lds[row * NT + col] = f2bf(acc[rt][ct][r]);
            }
        }
    __syncthreads();
    constexpr int NC = MT * NT / 2048;
    #pragma unroll
    for (int i = 0; i < NC; ++i) {
        int c = i * 256 + tid;
        int row = (c * 8) / NT;
        if (m0 + row < M)
            *(int4*)(C + (size_t)m0 * NT + c * 8) = *(const int4*)(lds + c * 8);
    }
}

// ---------------- fused gemm1 || scatter ----------------
// blocks [0,GB1): gemm1 on pre-converted xb. blocks [GB1,GB1+SB): atomic-free
// CSR scatter, 8 contiguous edges/thread; position = rowstart[dst] + rank.

__global__ __launch_bounds__(256) void gemm1_scatter_kernel(
    const u16* __restrict__ xb, const u16* __restrict__ W1T, u16* __restrict__ S1,
    const int* __restrict__ esrc, const int* __restrict__ edst,
    const float* __restrict__ ew, const int* __restrict__ rowstart,
    const int* __restrict__ rank, u32* __restrict__ csr) {
    __shared__ __align__(16) u16 lds[(64 + 256) * 64];
    int b = blockIdx.x;
    if (b < GB1) {
        gemm_body<64, 256, 4, NFEAT>(xb, W1T, S1, N_NODES, b, lds);
    } else {
        int e0 = ((b - GB1) * 256 + threadIdx.x) * 8;
        if (e0 < N_EDGES) {                       // 800000 % 8 == 0: full chunk
            int4 d0 = *(const int4*)(edst + e0),  d1 = *(const int4*)(edst + e0 + 4);
            int4 s0 = *(const int4*)(esrc + e0),  s1 = *(const int4*)(esrc + e0 + 4);
            float4 w0 = *(const float4*)(ew + e0), w1 = *(const float4*)(ew + e0 + 4);
            int4 r0 = *(const int4*)(rank + e0),  r1 = *(const int4*)(rank + e0 + 4);
            int d[8] = {d0.x, d0.y, d0.z, d0.w, d1.x, d1.y, d1.z, d1.w};
            int s[8] = {s0.x, s0.y, s0.z, s0.w, s1.x, s1.y, s1.z, s1.w};
            float w[8] = {w0.x, w0.y, w0.z, w0.w, w1.x, w1.y, w1.z, w1.w};
            int r[8] = {r0.x, r0.y, r0.z, r0.w, r1.x, r1.y, r1.z, r1.w};
            #pragma unroll
            for (int i = 0; i < 8; ++i) {
                int p = rowstart[d[i]] + r[i];
                csr[p] = (u32)s[i] | ((u32)f2bf(w[i]) << 16);   // cached: L2-merge
            }
        }
    }
}

// ---------------- gemm2: S2[M,64] = H[M,256] @ W2T[64][256]^T ----------------

__global__ __launch_bounds__(256) void gemm2_kernel(const u16* __restrict__ H,
                                                    const u16* __restrict__ W2T,
                                                    u16* __restrict__ S2, int M) {
    __shared__ __align__(16) u16 lds[(128 + 64) * 64];
    gemm_body<128, 64, 2, NHID>(H, W2T, S2, M, blockIdx.x, lds);
}

// ---------------- SpMM1 + bias + ReLU (one wave/node, 4 feats/lane, 8-way unroll) ----------------

__global__ __launch_bounds__(256) void spmm_bias_relu_kernel(
    const u16* __restrict__ S, const int* __restrict__ rowstart,
    const u32* __restrict__ csr, const float* __restrict__ bias,
    u16* __restrict__ H, int n) {
    int node = blockIdx.x * 4 + (threadIdx.x >> 6);
    if (node >= n) return;
    int lane = threadIdx.x & 63;
    int beg = rowstart[node], end = rowstart[node + 1];
    float a0 = 0.f, a1 = 0.f, a2 = 0.f, a3 = 0.f;
    int j = beg;
    for (; j + 8 <= end; j += 8) {           // 8 outstanding gathers
        u32 e[8];
        #pragma unroll
        for (int i = 0; i < 8; ++i) e[i] = csr[j + i];
        ushort4 v[8];
        #pragma unroll
        for (int i = 0; i < 8; ++i)
            v[i] = *(const ushort4*)(S + (size_t)(e[i] & 0xFFFFu) * NHID + lane * 4);
        #pragma unroll
        for (int i = 0; i < 8; ++i) {
            float w = bf2f((u16)(e[i] >> 16));
            a0 += w * bf2f(v[i].x); a1 += w * bf2f(v[i].y);
            a2 += w * bf2f(v[i].z); a3 += w * bf2f(v[i].w);
        }
    }
    for (; j < end; ++j) {
        u32 e0 = csr[j];
        float w = bf2f((u16)(e0 >> 16));
        ushort4 v0 = *(const ushort4*)(S + (size_t)(e0 & 0xFFFFu) * NHID + lane * 4);
        a0 += w * bf2f(v0.x); a1 += w * bf2f(v0.y);
        a2 += w * bf2f(v0.z); a3 += w * bf2f(v0.w);
    }
    float4 bv = *(const float4*)(bias + lane * 4);
    a0 = fmaxf(a0 + bv.x, 0.f);
    a1 = fmaxf(a1 + bv.y, 0.f);
    a2 = fmaxf(a2 + bv.z, 0.f);
    a3 = fmaxf(a3 + bv.w, 0.f);
    ushort4 o;
    o.x = f2bf(a0); o.y = f2bf(a1); o.z = f2bf(a2); o.w = f2bf(a3);
    *(ushort4*)(H + (size_t)node * NHID + lane * 4) = o;
}

// ---------------- SpMM2 + bias + log_softmax (one wave/node, 1 class/lane, 8-way) ----------------

__global__ __launch_bounds__(256) void spmm_bias_lsm_kernel(
    const u16* __restrict__ S, const int* __restrict__ rowstart,
    const u32* __restrict__ csr, const float* __restrict__ bias,
    float* __restrict__ out, int n) {
    int node = blockIdx.x * 4 + (threadIdx.x >> 6);
    if (node >= n) return;
    int lane = threadIdx.x & 63;
    int beg = rowstart[node], end = rowstart[node + 1];
    float acc = 0.f;
    int j = beg;
    for (; j + 8 <= end; j += 8) {
        u32 e[8];
        #pragma unroll
        for (int i = 0; i < 8; ++i) e[i] = csr[j + i];
        u16 v[8];
        #pragma unroll
        for (int i = 0; i < 8; ++i)
            v[i] = S[(size_t)(e[i] & 0xFFFFu) * NCLASS + lane];
        #pragma unroll
        for (int i = 0; i < 8; ++i)
            acc += bf2f((u16)(e[i] >> 16)) * bf2f(v[i]);
    }
    for (; j < end; ++j) {
        u32 e0 = csr[j];
        acc += bf2f((u16)(e0 >> 16)) * bf2f(S[(size_t)(e0 & 0xFFFFu) * NCLASS + lane]);
    }

    float x = acc + bias[lane];
    float m = x;
    #pragma unroll
    for (int off = 32; off > 0; off >>= 1) m = fmaxf(m, __shfl_xor(m, off));
    float e = expf(x - m);
    float ssum = e;
    #pragma unroll
    for (int off = 32; off > 0; off >>= 1) ssum += __shfl_xor(ssum, off);
    out[(size_t)node * NCLASS + lane] = x - m - logf(ssum);
}

// ---------------- launch ----------------

extern "C" void kernel_launch(void* const* d_in, const int* in_sizes, int n_in,
                              void* d_out, int out_size, void* d_ws, size_t ws_size,
                              hipStream_t stream) {
    const float* x  = (const float*)d_in[0];   // [50000,512]
    const float* W1 = (const float*)d_in[1];   // [512,256]
    const float* b1 = (const float*)d_in[2];   // [256]
    const float* W2 = (const float*)d_in[3];   // [256,64]
    const float* b2 = (const float*)d_in[4];   // [64]
    const float* ew = (const float*)d_in[5];   // [800000]
    const int* esrc = (const int*)d_in[6];
    const int* edst = (const int*)d_in[7];
    float* out = (float*)d_out;                // [50000,64]

    char* ws = (char*)d_ws;
    size_t off = 0;
    auto take = [&](size_t bytes) -> void* {
        off = (off + 255) & ~(size_t)255;
        void* p = ws + off;
        off += bytes;
        return p;
    };
    u16* xb       = (u16*)take((size_t)XELEMS * 2);            // 51.2 MB
    u16* S1       = (u16*)take((size_t)N_NODES * NHID * 2);    // 25.6 MB
    u16* H        = (u16*)take((size_t)N_NODES * NHID * 2);    // 25.6 MB
    u16* S2       = (u16*)take((size_t)N_NODES * NCLASS * 2);  // 6.4 MB
    u16* W1T      = (u16*)take((size_t)NHID * NFEAT * 2);      // [256][512]
    u16* W2T      = (u16*)take((size_t)NCLASS * NHID * 2);     // [64][256]
    int* deg      = (int*)take((size_t)DEG_PAD * 4);
    int* rowstart = (int*)take((size_t)(N_NODES + 1) * 4);
    int* rank     = (int*)take((size_t)N_EDGES * 4);           // 3.2 MB
    u32* csr      = (u32*)take((size_t)N_EDGES * 4);           // 3.2 MB packed
    (void)ws_size; (void)in_sizes; (void)n_in; (void)out_size;

    hipMemsetAsync(deg, 0, (size_t)DEG_PAD * 4, stream);
    prep_kernel<<<967, 256, 0, stream>>>(W1, W1T, W2, W2T, edst, deg, rank);
    scan_xcvt_kernel<<<1 + XCB, 1024, 0, stream>>>(deg, rowstart, N_NODES, x, xb);
    gemm1_scatter_kernel<<<GB1 + SB, 256, 0, stream>>>(xb, W1T, S1, esrc, edst, ew,
                                                       rowstart, rank, csr);
    spmm_bias_relu_kernel<<<(N_NODES + 3) / 4, 256, 0, stream>>>(
        S1, rowstart, csr, b1, H, N_NODES);
    gemm2_kernel<<<(N_NODES + 127) / 128, 256, 0, stream>>>(H, W2T, S2, N_NODES);
    spmm_bias_lsm_kernel<<<(N_NODES + 3) / 4, 256, 0, stream>>>(
        S2, rowstart, csr, b2, out, N_NODES);
}